// Round 12
// baseline (186.336 us; speedup 1.0000x reference)
//
#include <hip/hip_runtime.h>
#include <hip/hip_bf16.h>
#include <stdint.h>

#define M_DIM 8192
#define N_DIM 4096
#define K_DIM 4096

typedef __attribute__((ext_vector_type(4)))  int   int4v;
typedef __attribute__((ext_vector_type(16))) int   int16v;

// ---------------- pre-pass 1: per-row quantize x f32 -> i8, scale = rowmax/127 -------
__global__ __launch_bounds__(256) void quant_x_kernel(const float* __restrict__ x,
                                                      signed char* __restrict__ xq,
                                                      float* __restrict__ xs) {
    const int row = blockIdx.x;
    const int tid = threadIdx.x;
    const int wave = tid >> 6, lane = tid & 63;
    const float4* xr = (const float4*)(x + (size_t)row * K_DIM);

    float4 v[4];
    float m = 0.f;
    #pragma unroll
    for (int j = 0; j < 4; ++j) {
        v[j] = xr[j * 256 + tid];
        m = fmaxf(m, fmaxf(fmaxf(fabsf(v[j].x), fabsf(v[j].y)),
                           fmaxf(fabsf(v[j].z), fabsf(v[j].w))));
    }
    #pragma unroll
    for (int off = 32; off >= 1; off >>= 1) m = fmaxf(m, __shfl_down(m, off));
    __shared__ float wm[4];
    if (lane == 0) wm[wave] = m;
    __syncthreads();
    const float M = fmaxf(fmaxf(wm[0], wm[1]), fmaxf(wm[2], wm[3]));
    const float inv = M > 0.f ? 127.f / M : 0.f;
    if (tid == 0) xs[row] = M > 0.f ? M / 127.f : 0.f;

    char4* xo = (char4*)(xq + (size_t)row * K_DIM);
    #pragma unroll
    for (int j = 0; j < 4; ++j) {
        char4 q;
        q.x = (signed char)__float2int_rn(v[j].x * inv);
        q.y = (signed char)__float2int_rn(v[j].y * inv);
        q.z = (signed char)__float2int_rn(v[j].z * inv);
        q.w = (signed char)__float2int_rn(v[j].w * inv);
        xo[j * 256 + tid] = q;
    }
}

// ------- pre-pass 2: w f32 [K][N] -> sign(w) i8 transposed [N][K] (LDS transpose) ----
__global__ __launch_bounds__(256) void cvt_w_kernel(const float* __restrict__ w,
                                                    signed char* __restrict__ wT) {
    __shared__ signed char tile[64][68];   // pad breaks pow2 column-read stride
    const int t  = threadIdx.x;
    const int k0 = blockIdx.y * 64;
    const int n0 = blockIdx.x * 64;
    #pragma unroll
    for (int p = 0; p < 4; ++p) {
        int kk = p * 16 + (t >> 4);
        int nn = (t & 15) * 4;
        float4 v = *reinterpret_cast<const float4*>(&w[(size_t)(k0 + kk) * N_DIM + n0 + nn]);
        tile[kk][nn + 0] = v.x > 0.f ? 1 : (v.x < 0.f ? -1 : 0);
        tile[kk][nn + 1] = v.y > 0.f ? 1 : (v.y < 0.f ? -1 : 0);
        tile[kk][nn + 2] = v.z > 0.f ? 1 : (v.z < 0.f ? -1 : 0);
        tile[kk][nn + 3] = v.w > 0.f ? 1 : (v.w < 0.f ? -1 : 0);
    }
    __syncthreads();
    const int r = t >> 2;          // local n row
    const int c = (t & 3) * 16;    // local k byte
    int4v o;
    signed char* op = (signed char*)&o;
    #pragma unroll
    for (int j = 0; j < 16; ++j) op[j] = tile[c + j][r];
    *reinterpret_cast<int4v*>(&wT[(size_t)(n0 + r) * K_DIM + k0 + c]) = o;
}

// =====================================================================================
// 256x256 i8 GEMM, BK=128, mfma_i32_32x32x32_i8, double-buffered LDS, 1 barrier/tile:
//   C = relu( xs[row] * (Xq * signW^T) + bias )
// LDS: As[2][256*128] + Bs[2][256*128] = 128 KiB. Rows are 128 B -> 3-bit swizzle:
//   stored(row, c) = natural(row, c ^ f(row)),  f(row) = ((row>>1)&7)<<4
// Read col (carry-free): colX = (ks*32 + (lane>>5)*16) ^ (((lane>>1)&7)<<4).
// Bank audit (half-wave = 32 lanes): 8 (row>>1)-classes x 16 B cover all 32 banks,
// 4 rows/class -> exactly 4 dwords/bank = the service floor. (r10's 64-B rows only had
// 2 XOR bits -> 8/bank -> the measured 1.26e7 conflicts; this fixes that.)
// Write side: GLD sweep s covers dest rows s*64..+63 linearly; source col elems
//   = ((tid&7) ^ ((tid>>4)&7)) * 16   [row bits 3:1 = tid bits 6:4].
// Per tile t (NT=32): 24 ds_reads ; stage tile t+1 (8 GLD) ; 32 MFMA (32x32x32) ;
//   vmcnt(0) ; barrier.  Issue->wait distance ~2300 cyc >> HBM latency: no stall.
// C/D layout (verified r10): col=lane&31, row=(reg&3)+8*(reg>>2)+4*(lane>>5).
// =====================================================================================
#define BM 256
#define BN 256
#define BK 128
#define NT (K_DIM / BK)

#define GLD(gsrc, ldst) __builtin_amdgcn_global_load_lds( \
    (const __attribute__((address_space(1))) unsigned int*)(gsrc), \
    (__attribute__((address_space(3))) unsigned int*)(ldst), 16, 0, 0)

__global__ __launch_bounds__(512, 2) void gemm_i8_kernel(
    const signed char* __restrict__ A,   // [M][K] i8 (quantized x)
    const signed char* __restrict__ BT,  // [N][K] i8 = sign(w)^T
    const float* __restrict__ xsc,       // [M] row scales
    const float* __restrict__ bias,
    float* __restrict__ C)               // [M][N] f32
{
    __shared__ signed char As[2][256 * 128];   // 64 KiB
    __shared__ signed char Bs[2][256 * 128];   // 64 KiB

    const int tid  = threadIdx.x;
    const int wave = tid >> 6;
    const int lane = tid & 63;
    const int wm   = wave >> 2;        // 0..1 : wave M-half (rows wm*128..+127)
    const int wn   = wave & 3;         // 0..3 : wave N-slot (rows wn*64..+63 of B)

    // XCD-bijective swizzle (nwg = 512, divisible by 8)
    const int bid  = blockIdx.x;
    const int sbid = (bid & 7) * 64 + (bid >> 3);
    const int tn   = sbid & 15;
    const int tm   = sbid >> 4;
    const int bm   = tm * BM;
    const int bn   = tn * BN;

    // staging (write side of swizzle): GLD sweep s -> dest rows s*64 + (tid>>3),
    // dest col (tid&7)*16; source col = ((tid&7) ^ ((tid>>4)&7)) * 16
    const int srow = tid >> 3;                                // local row within sweep
    const int scol = (((tid & 7) ^ ((tid >> 4) & 7)) << 4);   // source col bytes

    // read side: 128-B rows, 3-bit XOR
    const int laneRow = (lane & 31) * 128;
    const int fsw  = ((lane >> 1) & 7) << 4;
    const int hb   = (lane >> 5) << 4;
    const int colX0 = (  0 + hb) ^ fsw;
    const int colX1 = ( 32 + hb) ^ fsw;
    const int colX2 = ( 64 + hb) ^ fsw;
    const int colX3 = ( 96 + hb) ^ fsw;
    const int Abase = wm * 128 * 128;   // wave's A row base (bytes)
    const int Bbase = wn * 64 * 128;    // wave's B row base (bytes)

    int16v acc[4][2] = {};   // [mb][nb] : 4x2 blocks of 32x32 = 128 rows x 64 cols

#define STAGE_T(G, R0, KOFS, LDSLOT) do { \
    _Pragma("unroll") \
    for (int s = 0; s < 4; ++s) \
        GLD((G) + (size_t)((R0) + s * 64 + srow) * K_DIM + (KOFS) + scol, \
            (LDSLOT) + s * 8192 + wave * 1024); \
  } while (0)

    // ---- prologue: stage tile0 -> slot0; drain; barrier ----
    STAGE_T(A,  bm, 0, As[0]);
    STAGE_T(BT, bn, 0, Bs[0]);
    asm volatile("s_waitcnt vmcnt(0)" ::: "memory");
    __builtin_amdgcn_s_barrier();

    int4v b[2][4];    // B frags [nb][ks]
    int4v aE[2][4];   // A frags mb 0-1
    int4v aL[2][4];   // A frags mb 2-3

    for (int t = 0; t < NT; ++t) {
        const int rd = t & 1;
        const char* Ar = (const char*)As[rd];
        const char* Br = (const char*)Bs[rd];
        const int kS = (t + 1 < NT ? t + 1 : NT - 1) * BK;   // tail reload never read

        // ---- B reads (8) + A mb0/mb1 reads (8), consumption order ----
        #pragma unroll
        for (int ks = 0; ks < 4; ++ks) {
            b[0][ks] = *(const int4v*)(Br + Bbase + 0 * 4096 + laneRow +
                                       (ks == 0 ? colX0 : ks == 1 ? colX1 : ks == 2 ? colX2 : colX3));
            b[1][ks] = *(const int4v*)(Br + Bbase + 1 * 4096 + laneRow +
                                       (ks == 0 ? colX0 : ks == 1 ? colX1 : ks == 2 ? colX2 : colX3));
        }
        #pragma unroll
        for (int mb = 0; mb < 2; ++mb)
            #pragma unroll
            for (int ks = 0; ks < 4; ++ks)
                aE[mb][ks] = *(const int4v*)(Ar + Abase + mb * 4096 + laneRow +
                                       (ks == 0 ? colX0 : ks == 1 ? colX1 : ks == 2 ? colX2 : colX3));

        // ---- stage tile t+1 into slot rd^1 (readers ran tile t-1; barrier-sequenced) ----
        STAGE_T(A,  bm, kS, As[rd ^ 1]);
        STAGE_T(BT, bn, kS, Bs[rd ^ 1]);

        // ---- MFMA mb0/mb1 (16) ----
        __builtin_amdgcn_s_setprio(1);
        #pragma unroll
        for (int mb = 0; mb < 2; ++mb)
            #pragma unroll
            for (int nb = 0; nb < 2; ++nb)
                #pragma unroll
                for (int ks = 0; ks < 4; ++ks)
                    acc[mb][nb] = __builtin_amdgcn_mfma_i32_32x32x32_i8(
                        aE[mb][ks], b[nb][ks], acc[mb][nb], 0, 0, 0);

        // ---- A mb2/mb3 reads (8), then MFMA mb2/mb3 (16) ----
        #pragma unroll
        for (int mb = 0; mb < 2; ++mb)
            #pragma unroll
            for (int ks = 0; ks < 4; ++ks)
                aL[mb][ks] = *(const int4v*)(Ar + Abase + (2 + mb) * 4096 + laneRow +
                                       (ks == 0 ? colX0 : ks == 1 ? colX1 : ks == 2 ? colX2 : colX3));
        #pragma unroll
        for (int mb = 0; mb < 2; ++mb)
            #pragma unroll
            for (int nb = 0; nb < 2; ++nb)
                #pragma unroll
                for (int ks = 0; ks < 4; ++ks)
                    acc[2 + mb][nb] = __builtin_amdgcn_mfma_i32_32x32x32_i8(
                        aL[mb][ks], b[nb][ks], acc[2 + mb][nb], 0, 0, 0);
        __builtin_amdgcn_s_setprio(0);

        // retire tile t+1's 8 GLDs (issued ~2300 cyc ago); release slots
        asm volatile("s_waitcnt vmcnt(0)" ::: "memory");
        __builtin_amdgcn_s_barrier();
    }

    // ---- epilogue (r10-verified 32x32 C/D): dequant + bias + relu ----
    #pragma unroll
    for (int mb = 0; mb < 4; ++mb) {
        const int row0 = bm + wm * 128 + mb * 32 + 4 * (lane >> 5);
        float4 s[4];
        #pragma unroll
        for (int q = 0; q < 4; ++q)
            s[q] = *reinterpret_cast<const float4*>(&xsc[row0 + 8 * q]);
        #pragma unroll
        for (int nb = 0; nb < 2; ++nb) {
            const int col = bn + wn * 64 + nb * 32 + (lane & 31);
            const float bvv = bias[col];
            #pragma unroll
            for (int q = 0; q < 4; ++q)
                #pragma unroll
                for (int j = 0; j < 4; ++j) {
                    const int row = row0 + 8 * q + j;
                    float v = (float)acc[mb][nb][q * 4 + j] * ((const float*)&s[q])[j] + bvv;
                    C[(size_t)row * N_DIM + col] = v > 0.f ? v : 0.f;
                }
        }
    }
}

// ---------------- fallback (only if ws_size too small): naive tiled fp32 -------------
__global__ void naive_kernel(const float* __restrict__ x, const float* __restrict__ w,
                             const float* __restrict__ b, float* __restrict__ out) {
    __shared__ float xs[16][16];
    __shared__ float ws[16][17];
    const int row = blockIdx.y * 16 + threadIdx.y;
    const int col = blockIdx.x * 16 + threadIdx.x;
    float acc = 0.f;
    for (int k0 = 0; k0 < K_DIM; k0 += 16) {
        xs[threadIdx.y][threadIdx.x] = x[(size_t)row * K_DIM + k0 + threadIdx.x];
        float wv = w[(size_t)(k0 + threadIdx.y) * N_DIM + col];
        ws[threadIdx.y][threadIdx.x] = wv > 0.f ? 1.f : (wv < 0.f ? -1.f : 0.f);
        __syncthreads();
        #pragma unroll
        for (int kk = 0; kk < 16; ++kk) acc += xs[threadIdx.y][kk] * ws[kk][threadIdx.x];
        __syncthreads();
    }
    float v = acc + b[col];
    out[(size_t)row * N_DIM + col] = v > 0.f ? v : 0.f;
}

extern "C" void kernel_launch(void* const* d_in, const int* in_sizes, int n_in,
                              void* d_out, int out_size, void* d_ws, size_t ws_size,
                              hipStream_t stream) {
    const float* x = (const float*)d_in[0];
    const float* w = (const float*)d_in[1];
    const float* b = (const float*)d_in[2];
    float* out = (float*)d_out;

    const size_t xq_bytes = (size_t)M_DIM * K_DIM;                 // 32 MiB i8
    const size_t wT_bytes = (size_t)K_DIM * N_DIM;                 // 16 MiB i8
    const size_t xs_bytes = (size_t)M_DIM * sizeof(float);         // 32 KiB

    if (ws_size >= xq_bytes + wT_bytes + xs_bytes) {
        signed char* xq = (signed char*)d_ws;
        signed char* wT = (signed char*)((char*)d_ws + xq_bytes);
        float*       xs = (float*)((char*)d_ws + xq_bytes + wT_bytes);
        quant_x_kernel<<<M_DIM, 256, 0, stream>>>(x, xq, xs);
        cvt_w_kernel<<<dim3(N_DIM / 64, K_DIM / 64), 256, 0, stream>>>(w, wT);
        gemm_i8_kernel<<<(M_DIM / BM) * (N_DIM / BN), 512, 0, stream>>>(xq, wT, xs, b, out);
    } else {
        naive_kernel<<<dim3(N_DIM / 16, M_DIM / 16), dim3(16, 16), 0, stream>>>(x, w, b, out);
    }
}

// Round 13
// 184.697 us; speedup vs baseline: 1.0089x; 1.0089x over previous
//
#include <hip/hip_runtime.h>
#include <hip/hip_bf16.h>
#include <stdint.h>

#define M_DIM 8192
#define N_DIM 4096
#define K_DIM 4096

typedef __attribute__((ext_vector_type(4))) int   int4v;
typedef __attribute__((ext_vector_type(4))) float floatx4;

// ---------------- pre-pass 1: per-row quantize x f32 -> i8, scale = rowmax/127 -------
__global__ __launch_bounds__(256) void quant_x_kernel(const float* __restrict__ x,
                                                      signed char* __restrict__ xq,
                                                      float* __restrict__ xs) {
    const int row = blockIdx.x;
    const int tid = threadIdx.x;
    const int wave = tid >> 6, lane = tid & 63;
    const float4* xr = (const float4*)(x + (size_t)row * K_DIM);

    float4 v[4];
    float m = 0.f;
    #pragma unroll
    for (int j = 0; j < 4; ++j) {
        v[j] = xr[j * 256 + tid];
        m = fmaxf(m, fmaxf(fmaxf(fabsf(v[j].x), fabsf(v[j].y)),
                           fmaxf(fabsf(v[j].z), fabsf(v[j].w))));
    }
    #pragma unroll
    for (int off = 32; off >= 1; off >>= 1) m = fmaxf(m, __shfl_down(m, off));
    __shared__ float wm[4];
    if (lane == 0) wm[wave] = m;
    __syncthreads();
    const float M = fmaxf(fmaxf(wm[0], wm[1]), fmaxf(wm[2], wm[3]));
    const float inv = M > 0.f ? 127.f / M : 0.f;
    if (tid == 0) xs[row] = M > 0.f ? M / 127.f : 0.f;

    char4* xo = (char4*)(xq + (size_t)row * K_DIM);
    #pragma unroll
    for (int j = 0; j < 4; ++j) {
        char4 q;
        q.x = (signed char)__float2int_rn(v[j].x * inv);
        q.y = (signed char)__float2int_rn(v[j].y * inv);
        q.z = (signed char)__float2int_rn(v[j].z * inv);
        q.w = (signed char)__float2int_rn(v[j].w * inv);
        xo[j * 256 + tid] = q;
    }
}

// ------- pre-pass 2: w f32 [K][N] -> sign(w) i8 transposed [N][K] (LDS transpose) ----
__global__ __launch_bounds__(256) void cvt_w_kernel(const float* __restrict__ w,
                                                    signed char* __restrict__ wT) {
    __shared__ signed char tile[64][68];   // pad breaks pow2 column-read stride
    const int t  = threadIdx.x;
    const int k0 = blockIdx.y * 64;
    const int n0 = blockIdx.x * 64;
    #pragma unroll
    for (int p = 0; p < 4; ++p) {
        int kk = p * 16 + (t >> 4);
        int nn = (t & 15) * 4;
        float4 v = *reinterpret_cast<const float4*>(&w[(size_t)(k0 + kk) * N_DIM + n0 + nn]);
        tile[kk][nn + 0] = v.x > 0.f ? 1 : (v.x < 0.f ? -1 : 0);
        tile[kk][nn + 1] = v.y > 0.f ? 1 : (v.y < 0.f ? -1 : 0);
        tile[kk][nn + 2] = v.z > 0.f ? 1 : (v.z < 0.f ? -1 : 0);
        tile[kk][nn + 3] = v.w > 0.f ? 1 : (v.w < 0.f ? -1 : 0);
    }
    __syncthreads();
    const int r = t >> 2;          // local n row
    const int c = (t & 3) * 16;    // local k byte
    int4v o;
    signed char* op = (signed char*)&o;
    #pragma unroll
    for (int j = 0; j < 16; ++j) op[j] = tile[c + j][r];
    *reinterpret_cast<int4v*>(&wT[(size_t)(n0 + r) * K_DIM + k0 + c]) = o;
}

// =====================================================================================
// 256x256 i8 GEMM, TWO K-tiles per barrier, 4 LDS slots (quad-buffer):
//   C = relu( xs[row] * (Xq * signW^T) + bias )
// Shape mfma_i32_16x16x64_i8; swizzle f(row)=((row>>1)&3)<<4 (verified 0-conflict).
// Pair P = (t, t+1), t even. Program order per pair (ONE barrier):
//   reads(t) x12 ; stage {A,B}(t+2)->slot (t+2)%4, {A,B}(t+3)->slot (t+3)%4 (8 GLD) ;
//   MFMA(t) x32 ; reads(t+1) x12 ; MFMA(t+1) x32 ; vmcnt(0) ; barrier.
// In-wave overlap: the wave issues MFMA(t) to the matrix pipe, then proceeds to issue
// reads(t+1) on the LDS pipe while MFMA(t) executes (counted lgkm waits gate MFMA(t+1)).
// Slot ledger (mod 4): pair reads {t,t+1}, stages {t+2,t+3} -- disjoint; each staged
// slot's readers ran in pair P-1, sequenced by P-1's end barrier. vmcnt(0) at pair end
// is >=1300 cyc after the last GLD issue (>= HBM latency): no latency stall.
// Frag regs reused across sub-tiles -> register count unchanged (2 waves/SIMD).
// =====================================================================================
#define BM 256
#define BN 256
#define BK 64
#define NT (K_DIM / BK)

#define GLD(gsrc, ldst) __builtin_amdgcn_global_load_lds( \
    (const __attribute__((address_space(1))) unsigned int*)(gsrc), \
    (__attribute__((address_space(3))) unsigned int*)(ldst), 16, 0, 0)

__global__ __launch_bounds__(512, 2) void gemm_i8_kernel(
    const signed char* __restrict__ A,   // [M][K] i8 (quantized x)
    const signed char* __restrict__ BT,  // [N][K] i8 = sign(w)^T
    const float* __restrict__ xsc,       // [M] row scales
    const float* __restrict__ bias,
    float* __restrict__ C)               // [M][N] f32
{
    __shared__ signed char As[4][2][128 * 64];   // 64 KiB
    __shared__ signed char Bs[4][2][128 * 64];   // 64 KiB

    const int tid  = threadIdx.x;
    const int wave = tid >> 6;
    const int lane = tid & 63;
    const int wm   = wave >> 2;        // 0..1 : wave M-half
    const int wn   = wave & 3;         // 0..3 : wave N-slot
    const int bh   = wn >> 1;          // B LDS half this wave reads
    const int brow0 = (wn & 1) * 64;   // row base inside that half

    // XCD-bijective swizzle (nwg = 512, divisible by 8)
    const int bid  = blockIdx.x;
    const int sbid = (bid & 7) * 64 + (bid >> 3);
    const int tn   = sbid & 15;
    const int tm   = sbid >> 4;
    const int bm   = tm * BM;
    const int bn   = tn * BN;

    // staging (write side of swizzle): dest linear o = tid*16; row = tid>>2;
    // source col = ((tid&3) ^ ((tid>>3)&3)) * 16   [row bits 2:1 = tid bits 4:3]
    const int srow = tid >> 2;
    const int scol = ((tid & 3) ^ ((tid >> 3) & 3)) * 16;

    // fragment read offsets (read side of swizzle)
    const int laneRow = (lane & 15) * 64;
    const int colX = ((lane >> 4) * 16) ^ (((lane >> 1) & 3) << 4);

    int4v acc[8][4] = {};

#define STAGE_HALF(G, R0, KOFS, LDST) do { \
    GLD((G) + (size_t)((R0) + srow) * K_DIM + (KOFS) + scol, (LDST) + wave * 1024); \
  } while (0)

    // ---- prologue: stage tiles 0,1 -> slots 0,1; drain; barrier ----
    STAGE_HALF(A,  bm,        0, As[0][0]);
    STAGE_HALF(A,  bm + 128,  0, As[0][1]);
    STAGE_HALF(BT, bn,        0, Bs[0][0]);
    STAGE_HALF(BT, bn + 128,  0, Bs[0][1]);
    STAGE_HALF(A,  bm,       BK, As[1][0]);
    STAGE_HALF(A,  bm + 128, BK, As[1][1]);
    STAGE_HALF(BT, bn,       BK, Bs[1][0]);
    STAGE_HALF(BT, bn + 128, BK, Bs[1][1]);
    asm volatile("s_waitcnt vmcnt(0)" ::: "memory");
    __builtin_amdgcn_s_barrier();

    int4v a[4];    // A frags rows 0-63 of wave half (reused per sub-tile)
    int4v a2[4];   // A frags rows 64-127
    int4v b[4];    // all 4 B n-frags

// one sub-tile: 12 ds_reads + 32 MFMA (no barrier, no manual waits)
#define SUBTILE(SLOT) do { \
    const char* Ar = (const char*)As[SLOT][wm]; \
    const char* Br = (const char*)Bs[SLOT][bh]; \
    a[0]  = *(const int4v*)(Ar + (0*16)*64 + laneRow + colX); \
    b[0]  = *(const int4v*)(Br + (brow0 +  0)*64 + laneRow + colX); \
    b[1]  = *(const int4v*)(Br + (brow0 + 16)*64 + laneRow + colX); \
    b[2]  = *(const int4v*)(Br + (brow0 + 32)*64 + laneRow + colX); \
    b[3]  = *(const int4v*)(Br + (brow0 + 48)*64 + laneRow + colX); \
    a[1]  = *(const int4v*)(Ar + (1*16)*64 + laneRow + colX); \
    a[2]  = *(const int4v*)(Ar + (2*16)*64 + laneRow + colX); \
    a[3]  = *(const int4v*)(Ar + (3*16)*64 + laneRow + colX); \
    a2[0] = *(const int4v*)(Ar + ((64 + 0*16))*64 + laneRow + colX); \
    a2[1] = *(const int4v*)(Ar + ((64 + 1*16))*64 + laneRow + colX); \
    a2[2] = *(const int4v*)(Ar + ((64 + 2*16))*64 + laneRow + colX); \
    a2[3] = *(const int4v*)(Ar + ((64 + 3*16))*64 + laneRow + colX); \
    __builtin_amdgcn_s_setprio(1); \
    _Pragma("unroll") \
    for (int mf = 0; mf < 4; ++mf) \
        _Pragma("unroll") \
        for (int nf = 0; nf < 4; ++nf) \
            acc[mf][nf] = __builtin_amdgcn_mfma_i32_16x16x64_i8( \
                a[mf], b[nf], acc[mf][nf], 0, 0, 0); \
    _Pragma("unroll") \
    for (int mf = 0; mf < 4; ++mf) \
        _Pragma("unroll") \
        for (int nf = 0; nf < 4; ++nf) \
            acc[4 + mf][nf] = __builtin_amdgcn_mfma_i32_16x16x64_i8( \
                a2[mf], b[nf], acc[4 + mf][nf], 0, 0, 0); \
    __builtin_amdgcn_s_setprio(0); \
  } while (0)

    for (int t = 0; t < NT; t += 2) {
        const int s0 = t & 3;              // slot of tile t
        const int s1 = (t + 1) & 3;        // slot of tile t+1
        const int s2 = (t + 2) & 3;        // stage slot (read in pair P-1)
        const int s3 = (t + 3) & 3;        // stage slot (read in pair P-1)
        const int k2 = (t + 2 < NT ? t + 2 : NT - 1) * BK;   // tail reloads never read
        const int k3 = (t + 3 < NT ? t + 3 : NT - 1) * BK;

        // sub-tile t reads first (data ready since end of pair P-1)
        {
            const char* Ar = (const char*)As[s0][wm];
            const char* Br = (const char*)Bs[s0][bh];
            a[0]  = *(const int4v*)(Ar + (0*16)*64 + laneRow + colX);
            b[0]  = *(const int4v*)(Br + (brow0 +  0)*64 + laneRow + colX);
            b[1]  = *(const int4v*)(Br + (brow0 + 16)*64 + laneRow + colX);
            b[2]  = *(const int4v*)(Br + (brow0 + 32)*64 + laneRow + colX);
            b[3]  = *(const int4v*)(Br + (brow0 + 48)*64 + laneRow + colX);
            a[1]  = *(const int4v*)(Ar + (1*16)*64 + laneRow + colX);
            a[2]  = *(const int4v*)(Ar + (2*16)*64 + laneRow + colX);
            a[3]  = *(const int4v*)(Ar + (3*16)*64 + laneRow + colX);
            a2[0] = *(const int4v*)(Ar + ((64 + 0*16))*64 + laneRow + colX);
            a2[1] = *(const int4v*)(Ar + ((64 + 1*16))*64 + laneRow + colX);
            a2[2] = *(const int4v*)(Ar + ((64 + 2*16))*64 + laneRow + colX);
            a2[3] = *(const int4v*)(Ar + ((64 + 3*16))*64 + laneRow + colX);
        }

        // all 8 GLDs for the pair, issued up-front (slots' readers ran in pair P-1)
        STAGE_HALF(A,  bm,       k2, As[s2][0]);
        STAGE_HALF(A,  bm + 128, k2, As[s2][1]);
        STAGE_HALF(BT, bn,       k2, Bs[s2][0]);
        STAGE_HALF(BT, bn + 128, k2, Bs[s2][1]);
        STAGE_HALF(A,  bm,       k3, As[s3][0]);
        STAGE_HALF(A,  bm + 128, k3, As[s3][1]);
        STAGE_HALF(BT, bn,       k3, Bs[s3][0]);
        STAGE_HALF(BT, bn + 128, k3, Bs[s3][1]);

        // MFMA(t) -- wave then runs ahead to issue reads(t+1) on the LDS pipe
        __builtin_amdgcn_s_setprio(1);
        #pragma unroll
        for (int mf = 0; mf < 4; ++mf)
            #pragma unroll
            for (int nf = 0; nf < 4; ++nf)
                acc[mf][nf] = __builtin_amdgcn_mfma_i32_16x16x64_i8(
                    a[mf], b[nf], acc[mf][nf], 0, 0, 0);
        #pragma unroll
        for (int mf = 0; mf < 4; ++mf)
            #pragma unroll
            for (int nf = 0; nf < 4; ++nf)
                acc[4 + mf][nf] = __builtin_amdgcn_mfma_i32_16x16x64_i8(
                    a2[mf], b[nf], acc[4 + mf][nf], 0, 0, 0);
        __builtin_amdgcn_s_setprio(0);

        // sub-tile t+1: reads overlap MFMA(t) execution; counted waits gate its MFMAs
        SUBTILE(s1);

        // drain the pair's 8 GLDs (issued >=1300 cyc ago); release slots
        asm volatile("s_waitcnt vmcnt(0)" ::: "memory");
        __builtin_amdgcn_s_barrier();
    }

    // ---- epilogue: dequant (per-row scale) + bias + relu, f32 store ----
    float bv[4];
    #pragma unroll
    for (int nf = 0; nf < 4; ++nf)
        bv[nf] = bias[bn + wn * 64 + nf * 16 + (lane & 15)];
    #pragma unroll
    for (int mf = 0; mf < 8; ++mf) {
        const int row0 = bm + wm * 128 + mf * 16 + (lane >> 4) * 4;
        float sr[4];
        #pragma unroll
        for (int r = 0; r < 4; ++r) sr[r] = xsc[row0 + r];
        #pragma unroll
        for (int nf = 0; nf < 4; ++nf) {
            const int col = bn + wn * 64 + nf * 16 + (lane & 15);
            float* cp = C + (size_t)row0 * N_DIM + col;
            #pragma unroll
            for (int r = 0; r < 4; ++r) {
                float v = (float)acc[mf][nf][r] * sr[r] + bv[nf];
                cp[(size_t)r * N_DIM] = v > 0.f ? v : 0.f;
            }
        }
    }
}

// ---------------- fallback (only if ws_size too small): naive tiled fp32 -------------
__global__ void naive_kernel(const float* __restrict__ x, const float* __restrict__ w,
                             const float* __restrict__ b, float* __restrict__ out) {
    __shared__ float xs[16][16];
    __shared__ float ws[16][17];
    const int row = blockIdx.y * 16 + threadIdx.y;
    const int col = blockIdx.x * 16 + threadIdx.x;
    float acc = 0.f;
    for (int k0 = 0; k0 < K_DIM; k0 += 16) {
        xs[threadIdx.y][threadIdx.x] = x[(size_t)row * K_DIM + k0 + threadIdx.x];
        float wv = w[(size_t)(k0 + threadIdx.y) * N_DIM + col];
        ws[threadIdx.y][threadIdx.x] = wv > 0.f ? 1.f : (wv < 0.f ? -1.f : 0.f);
        __syncthreads();
        #pragma unroll
        for (int kk = 0; kk < 16; ++kk) acc += xs[threadIdx.y][kk] * ws[kk][threadIdx.x];
        __syncthreads();
    }
    float v = acc + b[col];
    out[(size_t)row * N_DIM + col] = v > 0.f ? v : 0.f;
}

extern "C" void kernel_launch(void* const* d_in, const int* in_sizes, int n_in,
                              void* d_out, int out_size, void* d_ws, size_t ws_size,
                              hipStream_t stream) {
    const float* x = (const float*)d_in[0];
    const float* w = (const float*)d_in[1];
    const float* b = (const float*)d_in[2];
    float* out = (float*)d_out;

    const size_t xq_bytes = (size_t)M_DIM * K_DIM;                 // 32 MiB i8
    const size_t wT_bytes = (size_t)K_DIM * N_DIM;                 // 16 MiB i8
    const size_t xs_bytes = (size_t)M_DIM * sizeof(float);         // 32 KiB

    if (ws_size >= xq_bytes + wT_bytes + xs_bytes) {
        signed char* xq = (signed char*)d_ws;
        signed char* wT = (signed char*)((char*)d_ws + xq_bytes);
        float*       xs = (float*)((char*)d_ws + xq_bytes + wT_bytes);
        quant_x_kernel<<<M_DIM, 256, 0, stream>>>(x, xq, xs);
        cvt_w_kernel<<<dim3(N_DIM / 64, K_DIM / 64), 256, 0, stream>>>(w, wT);
        gemm_i8_kernel<<<(M_DIM / BM) * (N_DIM / BN), 512, 0, stream>>>(xq, wT, xs, b, out);
    } else {
        naive_kernel<<<dim3(N_DIM / 16, M_DIM / 16), dim3(16, 16), 0, stream>>>(x, w, b, out);
    }
}

// Round 14
// 180.009 us; speedup vs baseline: 1.0351x; 1.0260x over previous
//
#include <hip/hip_runtime.h>
#include <hip/hip_bf16.h>
#include <stdint.h>

#define M_DIM 8192
#define N_DIM 4096
#define K_DIM 4096

typedef __attribute__((ext_vector_type(4))) int   int4v;
typedef __attribute__((ext_vector_type(4))) float floatx4;

// ---------------- pre-pass 1: per-row quantize x f32 -> i8, scale = rowmax/127 -------
__global__ __launch_bounds__(256) void quant_x_kernel(const float* __restrict__ x,
                                                      signed char* __restrict__ xq,
                                                      float* __restrict__ xs) {
    const int row = blockIdx.x;
    const int tid = threadIdx.x;
    const int wave = tid >> 6, lane = tid & 63;
    const float4* xr = (const float4*)(x + (size_t)row * K_DIM);

    float4 v[4];
    float m = 0.f;
    #pragma unroll
    for (int j = 0; j < 4; ++j) {
        v[j] = xr[j * 256 + tid];
        m = fmaxf(m, fmaxf(fmaxf(fabsf(v[j].x), fabsf(v[j].y)),
                           fmaxf(fabsf(v[j].z), fabsf(v[j].w))));
    }
    #pragma unroll
    for (int off = 32; off >= 1; off >>= 1) m = fmaxf(m, __shfl_down(m, off));
    __shared__ float wm_s[4];
    if (lane == 0) wm_s[wave] = m;
    __syncthreads();
    const float M = fmaxf(fmaxf(wm_s[0], wm_s[1]), fmaxf(wm_s[2], wm_s[3]));
    const float inv = M > 0.f ? 127.f / M : 0.f;
    if (tid == 0) xs[row] = M > 0.f ? M / 127.f : 0.f;

    char4* xo = (char4*)(xq + (size_t)row * K_DIM);
    #pragma unroll
    for (int j = 0; j < 4; ++j) {
        char4 q;
        q.x = (signed char)__float2int_rn(v[j].x * inv);
        q.y = (signed char)__float2int_rn(v[j].y * inv);
        q.z = (signed char)__float2int_rn(v[j].z * inv);
        q.w = (signed char)__float2int_rn(v[j].w * inv);
        xo[j * 256 + tid] = q;
    }
}

// ------- pre-pass 2: w f32 [K][N] -> sign(w) i8 transposed [N][K] (LDS transpose) ----
__global__ __launch_bounds__(256) void cvt_w_kernel(const float* __restrict__ w,
                                                    signed char* __restrict__ wT) {
    __shared__ signed char tile[64][68];   // pad breaks pow2 column-read stride
    const int t  = threadIdx.x;
    const int k0 = blockIdx.y * 64;
    const int n0 = blockIdx.x * 64;
    #pragma unroll
    for (int p = 0; p < 4; ++p) {
        int kk = p * 16 + (t >> 4);
        int nn = (t & 15) * 4;
        float4 v = *reinterpret_cast<const float4*>(&w[(size_t)(k0 + kk) * N_DIM + n0 + nn]);
        tile[kk][nn + 0] = v.x > 0.f ? 1 : (v.x < 0.f ? -1 : 0);
        tile[kk][nn + 1] = v.y > 0.f ? 1 : (v.y < 0.f ? -1 : 0);
        tile[kk][nn + 2] = v.z > 0.f ? 1 : (v.z < 0.f ? -1 : 0);
        tile[kk][nn + 3] = v.w > 0.f ? 1 : (v.w < 0.f ? -1 : 0);
    }
    __syncthreads();
    const int r = t >> 2;          // local n row
    const int c = (t & 3) * 16;    // local k byte
    int4v o;
    signed char* op = (signed char*)&o;
    #pragma unroll
    for (int j = 0; j < 16; ++j) op[j] = tile[c + j][r];
    *reinterpret_cast<int4v*>(&wT[(size_t)(n0 + r) * K_DIM + k0 + c]) = o;
}

// =====================================================================================
// 256x256 i8 GEMM, 1024 threads / 16 waves (4M x 4N, 64x64 per wave), 4 waves/SIMD:
//   C = relu( xs[row] * (Xq * signW^T) + bias )
// acc = 64 VGPR/wave -> __launch_bounds__(1024,4) targets <=128 regs, 4 waves/SIMD:
// one wave's ds_reads overlap another's MFMAs (wave-level anti-phasing, m114 mechanism).
// r11's proven staging kept: 3 LDS slots per operand, staged TWO tiles ahead, one
// barrier per tile. 1024 threads stage a full [256][64] tile per GLD instruction.
// LDS: As[3][256*64] + Bs[3][256*64] = 96 KiB. Swizzle f(row)=((row>>1)&3)<<4
// (16-row fragments at the half-wave bank floor -- verified 0-conflict r7/r11).
// Per tile t: 8 ds_reads ; stage {A,B}(t+2) (2 GLD) ; 16 MFMA ; vmcnt(2) ; barrier.
// vmcnt ledger: outstanding at tile end = {A,B}(t+1) (issued t-1) + {A,B}(t+2)
// (issued t) = 4; vmcnt(2) retires the t+1 pair (issued a full tile ago: no stall).
// =====================================================================================
#define BM 256
#define BN 256
#define BK 64
#define NT (K_DIM / BK)

#define GLD(gsrc, ldst) __builtin_amdgcn_global_load_lds( \
    (const __attribute__((address_space(1))) unsigned int*)(gsrc), \
    (__attribute__((address_space(3))) unsigned int*)(ldst), 16, 0, 0)

__global__ __launch_bounds__(1024, 4) void gemm_i8_kernel(
    const signed char* __restrict__ A,   // [M][K] i8 (quantized x)
    const signed char* __restrict__ BT,  // [N][K] i8 = sign(w)^T
    const float* __restrict__ xsc,       // [M] row scales
    const float* __restrict__ bias,
    float* __restrict__ C)               // [M][N] f32
{
    __shared__ signed char As[3][256 * 64];   // 48 KiB
    __shared__ signed char Bs[3][256 * 64];   // 48 KiB

    const int tid  = threadIdx.x;
    const int wave = tid >> 6;
    const int lane = tid & 63;
    const int wm   = wave >> 2;        // 0..3 : wave M-slot (rows wm*64..+63)
    const int wn   = wave & 3;         // 0..3 : wave N-slot (cols wn*64..+63)

    // XCD-bijective swizzle (nwg = 512, divisible by 8)
    const int bid  = blockIdx.x;
    const int sbid = (bid & 7) * 64 + (bid >> 3);
    const int tn   = sbid & 15;
    const int tm   = sbid >> 4;
    const int bm   = tm * BM;
    const int bn   = tn * BN;

    // staging (write side of swizzle): dest linear o = tid*16 over [256][64];
    // row = tid>>2; source col = ((tid&3) ^ ((tid>>3)&3)) * 16  [row bits 2:1 = tid 4:3]
    const int srow = tid >> 2;
    const int scol = ((tid & 3) ^ ((tid >> 3) & 3)) * 16;

    // fragment read offsets (read side of swizzle)
    const int laneRow = (lane & 15) * 64;
    const int colX = ((lane >> 4) * 16) ^ (((lane >> 1) & 3) << 4);
    const int Abase = wm * 64 * 64;    // wave's A row base (bytes)
    const int Bbase = wn * 64 * 64;    // wave's B row base (bytes)

    int4v acc[4][4] = {};              // 64 VGPRs: 4x4 of 16x16 frags = 64x64

#define STAGE_T(G, R0, KOFS, LDSLOT) do { \
    GLD((G) + (size_t)((R0) + srow) * K_DIM + (KOFS) + scol, (LDSLOT) + wave * 1024); \
  } while (0)

    // ---- prologue: stage tiles 0,1 -> slots 0,1; retire tile-0 pair, keep tile-1 ----
    STAGE_T(A,  bm, 0,  As[0]);
    STAGE_T(BT, bn, 0,  Bs[0]);
    STAGE_T(A,  bm, BK, As[1]);
    STAGE_T(BT, bn, BK, Bs[1]);
    asm volatile("s_waitcnt vmcnt(2)" ::: "memory");
    __builtin_amdgcn_s_barrier();

    int4v a[4];    // A frags (reused per tile)
    int4v b[4];    // B frags

    int rd = 0;    // t % 3
    int st = 2;    // (t+2) % 3

    for (int t = 0; t < NT; ++t) {
        const char* Ar = (const char*)As[rd];
        const char* Br = (const char*)Bs[rd];
        const int kS = (t + 2 < NT ? t + 2 : NT - 1) * BK;   // tail reloads never read

        // ---- 8 ds_reads, consumption order ----
        a[0] = *(const int4v*)(Ar + Abase + (0*16)*64 + laneRow + colX);
        b[0] = *(const int4v*)(Br + Bbase + (0*16)*64 + laneRow + colX);
        b[1] = *(const int4v*)(Br + Bbase + (1*16)*64 + laneRow + colX);
        b[2] = *(const int4v*)(Br + Bbase + (2*16)*64 + laneRow + colX);
        b[3] = *(const int4v*)(Br + Bbase + (3*16)*64 + laneRow + colX);
        a[1] = *(const int4v*)(Ar + Abase + (1*16)*64 + laneRow + colX);
        a[2] = *(const int4v*)(Ar + Abase + (2*16)*64 + laneRow + colX);
        a[3] = *(const int4v*)(Ar + Abase + (3*16)*64 + laneRow + colX);

        // ---- stage {A,B}(t+2) into slot (t+2)%3 (readers ran in tile t-1) ----
        STAGE_T(A,  bm, kS, As[st]);
        STAGE_T(BT, bn, kS, Bs[st]);

        // ---- 16 MFMA (compiler-counted lgkm waits interleave with reads) ----
        __builtin_amdgcn_s_setprio(1);
        #pragma unroll
        for (int mf = 0; mf < 4; ++mf)
            #pragma unroll
            for (int nf = 0; nf < 4; ++nf)
                acc[mf][nf] = __builtin_amdgcn_mfma_i32_16x16x64_i8(
                    a[mf], b[nf], acc[mf][nf], 0, 0, 0);
        __builtin_amdgcn_s_setprio(0);

        // retire {A,B}(t+1) (issued a full tile ago); keep {A,B}(t+2) in flight
        asm volatile("s_waitcnt vmcnt(2)" ::: "memory");
        __builtin_amdgcn_s_barrier();

        rd = (rd == 2) ? 0 : rd + 1;
        st = (st == 2) ? 0 : st + 1;
    }

    // ---- epilogue: dequant (per-row scale) + bias + relu, f32 store ----
    float bv[4];
    #pragma unroll
    for (int nf = 0; nf < 4; ++nf)
        bv[nf] = bias[bn + wn * 64 + nf * 16 + (lane & 15)];
    #pragma unroll
    for (int mf = 0; mf < 4; ++mf) {
        const int row0 = bm + wm * 64 + mf * 16 + (lane >> 4) * 4;
        float sr[4];
        #pragma unroll
        for (int r = 0; r < 4; ++r) sr[r] = xsc[row0 + r];
        #pragma unroll
        for (int nf = 0; nf < 4; ++nf) {
            const int col = bn + wn * 64 + nf * 16 + (lane & 15);
            float* cp = C + (size_t)row0 * N_DIM + col;
            #pragma unroll
            for (int r = 0; r < 4; ++r) {
                float v = (float)acc[mf][nf][r] * sr[r] + bv[nf];
                cp[(size_t)r * N_DIM] = v > 0.f ? v : 0.f;
            }
        }
    }
}

// ---------------- fallback (only if ws_size too small): naive tiled fp32 -------------
__global__ void naive_kernel(const float* __restrict__ x, const float* __restrict__ w,
                             const float* __restrict__ b, float* __restrict__ out) {
    __shared__ float xs[16][16];
    __shared__ float ws[16][17];
    const int row = blockIdx.y * 16 + threadIdx.y;
    const int col = blockIdx.x * 16 + threadIdx.x;
    float acc = 0.f;
    for (int k0 = 0; k0 < K_DIM; k0 += 16) {
        xs[threadIdx.y][threadIdx.x] = x[(size_t)row * K_DIM + k0 + threadIdx.x];
        float wv = w[(size_t)(k0 + threadIdx.y) * N_DIM + col];
        ws[threadIdx.y][threadIdx.x] = wv > 0.f ? 1.f : (wv < 0.f ? -1.f : 0.f);
        __syncthreads();
        #pragma unroll
        for (int kk = 0; kk < 16; ++kk) acc += xs[threadIdx.y][kk] * ws[kk][threadIdx.x];
        __syncthreads();
    }
    float v = acc + b[col];
    out[(size_t)row * N_DIM + col] = v > 0.f ? v : 0.f;
}

extern "C" void kernel_launch(void* const* d_in, const int* in_sizes, int n_in,
                              void* d_out, int out_size, void* d_ws, size_t ws_size,
                              hipStream_t stream) {
    const float* x = (const float*)d_in[0];
    const float* w = (const float*)d_in[1];
    const float* b = (const float*)d_in[2];
    float* out = (float*)d_out;

    const size_t xq_bytes = (size_t)M_DIM * K_DIM;                 // 32 MiB i8
    const size_t wT_bytes = (size_t)K_DIM * N_DIM;                 // 16 MiB i8
    const size_t xs_bytes = (size_t)M_DIM * sizeof(float);         // 32 KiB

    if (ws_size >= xq_bytes + wT_bytes + xs_bytes) {
        signed char* xq = (signed char*)d_ws;
        signed char* wT = (signed char*)((char*)d_ws + xq_bytes);
        float*       xs = (float*)((char*)d_ws + xq_bytes + wT_bytes);
        quant_x_kernel<<<M_DIM, 256, 0, stream>>>(x, xq, xs);
        cvt_w_kernel<<<dim3(N_DIM / 64, K_DIM / 64), 256, 0, stream>>>(w, wT);
        gemm_i8_kernel<<<(M_DIM / BM) * (N_DIM / BN), 1024, 0, stream>>>(xq, wT, xs, b, out);
    } else {
        naive_kernel<<<dim3(N_DIM / 16, M_DIM / 16), dim3(16, 16), 0, stream>>>(x, w, b, out);
    }
}